// Round 3
// baseline (63.090 us; speedup 1.0000x reference)
//
#include <hip/hip_runtime.h>

// out = FWHT(in1 * in2) / sqrt(4096), rows of length N=4096, fp32.
// One row per 256-thread block; 16 elements/thread in registers.
// 12 index bits partitioned into 3 register-held groups of 4; 16-pt
// in-register FWHT per phase, LDS exchange between phases (pad l+(l>>5):
// <=2-way bank aliasing, free on wave64/32-bank).
// R2: nt output stores (write-allocate pollution fix, 77->63us).
// R3: cache-partition the input reads. Inputs are 256 MiB == L3 capacity and
// thrash to ~50% hit. nt-load a fixed 1/4 of rows (never allocate in L3) so
// the remaining 3/4 (~201 MB) fits resident across graph replays.

#define ROW_N 4096
#define NTHREADS 256

typedef float v4f __attribute__((ext_vector_type(4)));

__device__ __forceinline__ int lpad(int l) { return l + (l >> 5); }

__device__ __forceinline__ void fwht16(float x[16]) {
#pragma unroll
    for (int m = 1; m < 16; m <<= 1) {
#pragma unroll
        for (int r = 0; r < 16; ++r) {
            if ((r & m) == 0) {
                const float u = x[r];
                const float v = x[r | m];
                x[r]     = u + v;
                x[r | m] = u - v;
            }
        }
    }
}

__launch_bounds__(NTHREADS)
__global__ void fwht_mul_kernel(const float* __restrict__ a,
                                const float* __restrict__ b,
                                float* __restrict__ out,
                                int nt_rows) {
    __shared__ float lds[ROW_N + (ROW_N >> 5)];  // 4224 floats = 16.9 KiB

    const int t = threadIdx.x;
    const long long row = blockIdx.x;
    const float* __restrict__ pa = a + row * ROW_N;
    const float* __restrict__ pb = b + row * ROW_N;
    float* __restrict__ po = out + row * ROW_N;

    float x[16];

    // ---- Phase 1: regs hold element bits {0,1,10,11}; float4 loads ----
    if (blockIdx.x < (unsigned)nt_rows) {
        // streaming slice: don't allocate in L3
#pragma unroll
        for (int r4 = 0; r4 < 4; ++r4) {
            const int off = (r4 << 10) + (t << 2);
            const v4f va = __builtin_nontemporal_load(
                reinterpret_cast<const v4f*>(pa + off));
            const v4f vb = __builtin_nontemporal_load(
                reinterpret_cast<const v4f*>(pb + off));
#pragma unroll
            for (int j = 0; j < 4; ++j) x[r4 * 4 + j] = va[j] * vb[j];
        }
    } else {
        // resident slice: normal cached loads (stays in Infinity Cache)
#pragma unroll
        for (int r4 = 0; r4 < 4; ++r4) {
            const int off = (r4 << 10) + (t << 2);
            const v4f va = *reinterpret_cast<const v4f*>(pa + off);
            const v4f vb = *reinterpret_cast<const v4f*>(pb + off);
#pragma unroll
            for (int j = 0; j < 4; ++j) x[r4 * 4 + j] = va[j] * vb[j];
        }
    }
    fwht16(x);  // butterflies over bits 0,1,10,11

    // ---- Exchange 1: to regs = bits {2..5} ----
#pragma unroll
    for (int r = 0; r < 16; ++r) {
        const int l = (r & 3) | (t << 2) | ((r >> 2) << 10);
        lds[lpad(l)] = x[r];
    }
    __syncthreads();
#pragma unroll
    for (int r = 0; r < 16; ++r) {
        const int l = (t & 3) | (r << 2) | ((t >> 2) << 6);
        x[r] = lds[lpad(l)];
    }
    fwht16(x);  // butterflies over bits 2..5

    // ---- Exchange 2: to regs = bits {6..9} ----
    __syncthreads();
#pragma unroll
    for (int r = 0; r < 16; ++r) {
        const int l = (t & 3) | (r << 2) | ((t >> 2) << 6);
        lds[lpad(l)] = x[r];
    }
    __syncthreads();
#pragma unroll
    for (int r = 0; r < 16; ++r) {
        const int l = (t & 63) | (r << 6) | ((t >> 6) << 10);
        x[r] = lds[lpad(l)];
    }
    fwht16(x);  // butterflies over bits 6..9

    // ---- Store (scale = 1/64), non-temporal: don't pollute L2/L3 ----
#pragma unroll
    for (int r = 0; r < 16; ++r) {
        const int l = (t & 63) | (r << 6) | ((t >> 6) << 10);
        __builtin_nontemporal_store(x[r] * 0.015625f, po + l);
    }
}

extern "C" void kernel_launch(void* const* d_in, const int* in_sizes, int n_in,
                              void* d_out, int out_size, void* d_ws, size_t ws_size,
                              hipStream_t stream) {
    const float* a = (const float*)d_in[0];
    const float* b = (const float*)d_in[1];
    float* out = (float*)d_out;
    const int rows = in_sizes[0] / ROW_N;  // 8192
    const int nt_rows = rows / 4;          // streaming slice; rest stays L3-resident
    hipLaunchKernelGGL(fwht_mul_kernel, dim3(rows), dim3(NTHREADS), 0, stream,
                       a, b, out, nt_rows);
}